// Round 3
// baseline (611.027 us; speedup 1.0000x reference)
//
#include <hip/hip_runtime.h>
#include <hip/hip_bf16.h>

// Problem constants
#define BROWS 8192      // B*N = 8*1024
#define DDIM 3
#define CDIM 64
#define KF 8192         // F = 2*C*C
#define NINV 512
#define NEQ 1024        // per head
#define NTOT 2560       // 512 + 1024 + 1024
#define BAS 16
#define UEQ 64

// Packed-tile layouts (producers and GEMM agree):
//  A: tile (mb, kt) = 256 rows x 32 k bf16 = 16 KB at byte ((mb*256+kt) << 14)
//  B: tile (nb, kt) = 320 rows x 32 k bf16 = 20 KB at byte ((nb*256+kt) * 20480)
//  Within a tile, element (rloc, kk):
//    logical chunk lc = (kk>>3)&3, phys = (lc + (rloc>>1)) & 3  (bank swizzle)
//    byte = rloc*64 + phys*16 + (kk&7)*2
// Staging is a linear memcpy per tile.

typedef float f32x4 __attribute__((ext_vector_type(4)));
typedef __bf16 bf16x8_t __attribute__((ext_vector_type(8)));
typedef __bf16 bf16x4_t __attribute__((ext_vector_type(4)));

__device__ __forceinline__ void async_copy16(const void* g, void* l) {
    __builtin_amdgcn_global_load_lds(
        (__attribute__((address_space(1))) void*)(g),
        (__attribute__((address_space(3))) void*)(l), 16, 0, 0);
}

// ---------------------------------------------------------------------------
// Kernel 1: per-row l2norm + Gram blocks -> packed feats tiles [32][256][16KB]
// ---------------------------------------------------------------------------
__global__ __launch_bounds__(256) void feats_kernel(
    const float* __restrict__ t1, const float* __restrict__ t2,
    const float* __restrict__ u1, const float* __restrict__ u2,
    __hip_bfloat16* __restrict__ feats)
{
    const int row = blockIdx.x;
    const int tid = threadIdx.x;
    __shared__ float sT[2 * DDIM * CDIM];   // [head][d][c]
    __shared__ float sU[2 * DDIM * CDIM];   // scaled u

    const size_t base = (size_t)row * (DDIM * CDIM);
    if (tid < 192) {
        sT[tid]       = t1[base + tid];
        sT[192 + tid] = t2[base + tid];
        sU[tid]       = u1[base + tid];
        sU[192 + tid] = u2[base + tid];
    }
    __syncthreads();
    if (tid < 128) {
        const int h = tid >> 6, c = tid & 63;
        float* U = sU + h * 192;
        float sq = U[c] * U[c] + U[64 + c] * U[64 + c] + U[128 + c] * U[128 + c];
        float s = 1.0f / sqrtf(fmaxf(sq, 0.01f));
        U[c] *= s; U[64 + c] *= s; U[128 + c] *= s;
    }
    __syncthreads();
    // thread -> (h, i, j-half); covers one 32-k tile span = one packed 64B line
    const int h  = tid >> 7;            // 0..1
    const int i  = (tid >> 1) & 63;     // 0..63
    const int jh = (tid & 1) * 32;      // 0 or 32
    const float* T = sT + h * 192;
    const float* U = sU + h * 192;
    const float ti0 = T[i], ti1 = T[64 + i], ti2 = T[128 + i];

    const int kbase = h * 4096 + i * 64 + jh;   // 32-aligned global k
    const int kt    = kbase >> 5;
    const int mb    = row >> 8, rloc = row & 255;
    char* line = (char*)feats + (((size_t)(mb * 256 + kt)) << 14) + rloc * 64;

    #pragma unroll
    for (int g = 0; g < 4; ++g) {                 // logical chunk
        const int phys = (g + (rloc >> 1)) & 3;
        #pragma unroll
        for (int half = 0; half < 2; ++half) {
            const int j = jh + g * 8 + half * 4;  // within-head col, mult of 4
            const float4 u0 = *reinterpret_cast<const float4*>(U + j);
            const float4 u1 = *reinterpret_cast<const float4*>(U + 64 + j);
            const float4 u2 = *reinterpret_cast<const float4*>(U + 128 + j);
            bf16x4_t v;
            v[0] = (__bf16)(ti0 * u0.x + ti1 * u1.x + ti2 * u2.x);
            v[1] = (__bf16)(ti0 * u0.y + ti1 * u1.y + ti2 * u2.y);
            v[2] = (__bf16)(ti0 * u0.z + ti1 * u1.z + ti2 * u2.z);
            v[3] = (__bf16)(ti0 * u0.w + ti1 * u1.w + ti2 * u2.w);
            *reinterpret_cast<bf16x4_t*>(line + phys * 16 + half * 8) = v;
        }
    }
}

// ---------------------------------------------------------------------------
// Kernel 2: transpose+convert W (K x N fp32) -> packed WT tiles [8][256][20KB]
// ---------------------------------------------------------------------------
__global__ __launch_bounds__(256) void wt_kernel(
    const float* __restrict__ W_inv, const float* __restrict__ W_eq,
    __hip_bfloat16* __restrict__ WT)
{
    __shared__ float tile[32][33];
    const int tid = threadIdx.x;
    const int tx = tid & 31;          // n within tile (load)
    const int ty = tid >> 5;          // 0..7
    const int n0 = blockIdx.x * 32;   // output column block (0..2559)
    const int k0 = blockIdx.y * 32;   // K block (0..8191)

    const float* src; int ldn, nl0;
    if (n0 < NINV)            { src = W_inv;                       ldn = NINV; nl0 = n0; }
    else if (n0 < NINV + NEQ) { src = W_eq;                        ldn = NEQ;  nl0 = n0 - NINV; }
    else                      { src = W_eq + (size_t)KF * NEQ;     ldn = NEQ;  nl0 = n0 - NINV - NEQ; }

    #pragma unroll
    for (int i = 0; i < 4; ++i) {
        int kl = ty + i * 8;
        tile[kl][tx] = src[(size_t)(k0 + kl) * ldn + nl0 + tx];
    }
    __syncthreads();
    // store phase: each thread packs 4 consecutive k for one n (8 B store)
    const int n_l = tid >> 3;         // 0..31
    const int k4  = (tid & 7) * 4;    // 0..28
    bf16x4_t v;
    #pragma unroll
    for (int q = 0; q < 4; ++q) v[q] = (__bf16)tile[k4 + q][n_l];

    const int n    = n0 + n_l;
    const int nb   = n / 320, rloc = n - nb * 320;
    const int kt   = k0 >> 5;
    const int lc   = (k4 >> 3) & 3, e = k4 & 7;
    const int phys = (lc + (rloc >> 1)) & 3;
    char* dst = (char*)WT + ((size_t)(nb * 256 + kt)) * 20480
              + rloc * 64 + phys * 16 + e * 2;
    *reinterpret_cast<bf16x4_t*>(dst) = v;
}

// ---------------------------------------------------------------------------
// Kernel 3: bf16 MFMA GEMM on packed tiles. BM=256 x BN=320, grid = exactly
// 256 blocks (1/CU, no tail). 512 threads = 8 waves (4m x 2n), wave tile
// 64x160. 4 LDS buffers (144 KB), prefetch distance 3, static indices.
// Waves 0-3 stage A (4 x 16B/phase), waves 4-7 stage B (5/phase).
// R1: + s_setprio(1) around the compute region (T5) — counted-vmcnt schedule
//     gives the CU scheduler wave role diversity to arbitrate.
// ---------------------------------------------------------------------------
#define BM 256
#define BN 320
#define BK 32
#define ATILE 16384
#define BTILE 20480

__global__ __launch_bounds__(512, 2) void gemm_kernel(
    const __hip_bfloat16* __restrict__ A,   // packed [32][256][16KB]
    const __hip_bfloat16* __restrict__ BT,  // packed [8][256][20KB]
    const float* __restrict__ b_inv, const float* __restrict__ g_inv,
    const float* __restrict__ be_inv,
    const float* __restrict__ b_eq,  const float* __restrict__ g_eq,
    const float* __restrict__ be_eq,
    float* __restrict__ out_inv,            // d_out: [BROWS][NINV]
    float* __restrict__ Yeq)                // ws:    [BROWS][2048]
{
    __shared__ alignas(16) __hip_bfloat16 AsBuf[4][BM * BK];  // 4 x 16 KB
    __shared__ alignas(16) __hip_bfloat16 BsBuf[4][BN * BK];  // 4 x 20 KB

    const int tid  = threadIdx.x;
    const int wave = tid >> 6;
    const int lane = tid & 63;
    const bool aWave = wave < 4;

    // 256 blocks: xcd = b%8 owns 4 contiguous m-stripes, n fastest.
    const int b    = blockIdx.x;
    const int xcd  = b & 7;
    const int slot = b >> 3;            // 0..31
    const int nb   = slot & 7;          // 0..7
    const int mb   = xcd * 4 + (slot >> 3);
    const int n0   = nb * BN;
    const int m0   = mb * BM;

    const char* pA = (const char*)A  + ((size_t)mb << 22);        // mb*4MB
    const char* pB = (const char*)BT + (size_t)nb * 256 * BTILE;  // nb*5MB

    // staging offsets (linear memcpy within a tile)
    const int aoff = wave * 4096 + lane * 16;         // waves 0-3
    const int boff = (wave - 4) * 5120 + lane * 16;   // waves 4-7

    // ds_read chunk swizzle (row-parity based, tile-term-independent)
    const int chnk = (((lane >> 4) + ((lane & 15) >> 1)) & 3) * 8;
    const int wm = (wave & 3) * 64;
    const int wn = (wave >> 2) * 160;
    const int l15 = lane & 15;

    f32x4 acc[4][10] = {};

#define ISSUE(bufi, t)                                                        \
    do {                                                                      \
        if (aWave) {                                                          \
            _Pragma("unroll")                                                 \
            for (int j = 0; j < 4; ++j)                                       \
                async_copy16(pA + (size_t)(t) * ATILE + aoff + j * 1024,      \
                             (char*)&AsBuf[bufi][0] + aoff + j * 1024);       \
        } else {                                                              \
            _Pragma("unroll")                                                 \
            for (int j = 0; j < 5; ++j)                                       \
                async_copy16(pB + (size_t)(t) * BTILE + boff + j * 1024,      \
                             (char*)&BsBuf[bufi][0] + boff + j * 1024);       \
        }                                                                     \
    } while (0)

#define COMPUTE(bufi)                                                         \
    do {                                                                      \
        bf16x8_t a_[4];                                                       \
        _Pragma("unroll")                                                     \
        for (int mt = 0; mt < 4; ++mt)                                        \
            a_[mt] = *reinterpret_cast<const bf16x8_t*>(                      \
                &AsBuf[bufi][(wm + mt * 16 + l15) * BK + chnk]);              \
        _Pragma("unroll")                                                     \
        for (int nt = 0; nt < 10; ++nt) {                                     \
            bf16x8_t b_ = *reinterpret_cast<const bf16x8_t*>(                 \
                &BsBuf[bufi][(wn + nt * 16 + l15) * BK + chnk]);              \
            _Pragma("unroll")                                                 \
            for (int mt = 0; mt < 4; ++mt)                                    \
                acc[mt][nt] = __builtin_amdgcn_mfma_f32_16x16x32_bf16(        \
                    a_[mt], b_, acc[mt][nt], 0, 0, 0);                        \
        }                                                                     \
    } while (0)

#define WAITAB(na, nb_)                                                       \
    do {                                                                      \
        if (aWave) asm volatile("s_waitcnt vmcnt(" #na ")" ::: "memory");     \
        else       asm volatile("s_waitcnt vmcnt(" #nb_ ")" ::: "memory");    \
    } while (0)

#define PHASE(bufc, bufp, t)                                                  \
    do {                                                                      \
        ISSUE(bufp, t + 3);                                                   \
        WAITAB(12, 15);                                                       \
        __builtin_amdgcn_s_barrier();                                         \
        asm volatile("" ::: "memory");                                        \
        __builtin_amdgcn_s_setprio(1);                                        \
        COMPUTE(bufc);                                                        \
        __builtin_amdgcn_s_setprio(0);                                        \
        asm volatile("" ::: "memory");                                        \
        __builtin_amdgcn_s_barrier();                                         \
    } while (0)

    // prologue: tiles 0,1,2 -> bufs 0,1,2
    ISSUE(0, 0);
    ISSUE(1, 1);
    ISSUE(2, 2);

    for (int i4 = 0; i4 < 63; ++i4) {
        const int t = i4 * 4;
        PHASE(0, 3, t);
        PHASE(1, 0, t + 1);
        PHASE(2, 1, t + 2);
        PHASE(3, 2, t + 3);
    }
    // tail: tiles 252..255 in bufs 0..3
    ISSUE(3, 255);
    WAITAB(12, 15);
    __builtin_amdgcn_s_barrier();
    asm volatile("" ::: "memory");
    __builtin_amdgcn_s_setprio(1);
    COMPUTE(0);
    __builtin_amdgcn_s_setprio(0);
    asm volatile("" ::: "memory");
    __builtin_amdgcn_s_barrier();

    WAITAB(8, 10);
    __builtin_amdgcn_s_barrier();
    asm volatile("" ::: "memory");
    __builtin_amdgcn_s_setprio(1);
    COMPUTE(1);
    __builtin_amdgcn_s_setprio(0);
    asm volatile("" ::: "memory");
    __builtin_amdgcn_s_barrier();

    WAITAB(4, 5);
    __builtin_amdgcn_s_barrier();
    asm volatile("" ::: "memory");
    __builtin_amdgcn_s_setprio(1);
    COMPUTE(2);
    __builtin_amdgcn_s_setprio(0);
    asm volatile("" ::: "memory");
    __builtin_amdgcn_s_barrier();

    asm volatile("s_waitcnt vmcnt(0)" ::: "memory");
    __builtin_amdgcn_s_barrier();
    asm volatile("" ::: "memory");
    __builtin_amdgcn_s_setprio(1);
    COMPUTE(3);
    __builtin_amdgcn_s_setprio(0);

    // epilogue: y = relu(g * (acc + b) / sqrt(1.001) + be), params fused
    const float RSQ = 0.9995003746877732f;
    #pragma unroll
    for (int nt = 0; nt < 10; ++nt) {
        const int gn = n0 + wn + nt * 16 + l15;
        float bbp, gg, bep;
        if (gn < NINV) {
            bbp = b_inv[gn]; gg = g_inv[gn]; bep = be_inv[gn];
        } else {
            const int e = gn - NINV, hh = e >> 10, nl = e & 1023;
            bbp = b_eq[hh * NEQ + nl]; gg = g_eq[hh * NEQ + nl]; bep = be_eq[hh * NEQ + nl];
        }
        gg *= RSQ;
        #pragma unroll
        for (int mt = 0; mt < 4; ++mt) {
            const int gmb = m0 + wm + mt * 16 + ((lane >> 4) << 2);
            #pragma unroll
            for (int rr = 0; rr < 4; ++rr) {
                float y = fmaxf(gg * (acc[mt][nt][rr] + bbp) + bep, 0.0f);
                const size_t gm = gmb + rr;
                if (gn < NINV) out_inv[gm * NINV + gn] = y;
                else           Yeq[gm * 2048 + (gn - NINV)] = y;
            }
        }
    }
#undef PHASE
#undef WAITAB
#undef COMPUTE
#undef ISSUE
}

// ---------------------------------------------------------------------------
// Kernel 4: basis recombine
// ---------------------------------------------------------------------------
__global__ __launch_bounds__(128) void eqcomb_kernel(
    const float* __restrict__ Yeq,   // [BROWS][2048]
    const float* __restrict__ V1, const float* __restrict__ V2,
    float* __restrict__ out_eq)      // [BROWS][3][128]
{
    const int row = blockIdx.x;
    const int tid = threadIdx.x;     // 128
    __shared__ float sV[2][DDIM][BAS];
    if (tid < 96) {
        const int h = tid / 48, rem = tid % 48;
        const float* V = h ? V2 : V1;
        sV[h][rem / BAS][rem % BAS] = V[(size_t)row * (DDIM * BAS) + rem];
    }
    __syncthreads();
    const int l = tid >> 6, u = tid & 63;
    const float4* y4 = reinterpret_cast<const float4*>(
        Yeq + (size_t)row * 2048 + l * 1024 + u * BAS);
    float a0 = 0.f, a1 = 0.f, a2 = 0.f;
    #pragma unroll
    for (int q = 0; q < 4; ++q) {
        float4 w = y4[q];
        const float* v0 = sV[l][0] + q * 4;
        const float* v1 = sV[l][1] + q * 4;
        const float* v2 = sV[l][2] + q * 4;
        a0 += w.x * v0[0] + w.y * v0[1] + w.z * v0[2] + w.w * v0[3];
        a1 += w.x * v1[0] + w.y * v1[1] + w.z * v1[2] + w.w * v1[3];
        a2 += w.x * v2[0] + w.y * v2[1] + w.z * v2[2] + w.w * v2[3];
    }
    float* o = out_eq + (size_t)row * (DDIM * 128);
    o[0 * 128 + l * 64 + u] = a0;
    o[1 * 128 + l * 64 + u] = a1;
    o[2 * 128 + l * 64 + u] = a2;
}

// ---------------------------------------------------------------------------
extern "C" void kernel_launch(void* const* d_in, const int* in_sizes, int n_in,
                              void* d_out, int out_size, void* d_ws, size_t ws_size,
                              hipStream_t stream) {
    const float* t1    = (const float*)d_in[0];
    const float* t2    = (const float*)d_in[1];
    const float* u1    = (const float*)d_in[2];
    const float* u2    = (const float*)d_in[3];
    const float* V1    = (const float*)d_in[4];
    const float* V2    = (const float*)d_in[5];
    const float* W_inv = (const float*)d_in[6];
    const float* b_inv = (const float*)d_in[7];
    const float* g_inv = (const float*)d_in[8];
    const float* be_inv= (const float*)d_in[9];
    const float* W_eq  = (const float*)d_in[10];
    const float* b_eq  = (const float*)d_in[11];
    const float* g_eq  = (const float*)d_in[12];
    const float* be_eq = (const float*)d_in[13];
    float* out = (float*)d_out;

    // workspace layout (bytes)
    char* ws = (char*)d_ws;
    __hip_bfloat16* feats = (__hip_bfloat16*)(ws);                       // 134,217,728 (packed)
    __hip_bfloat16* WT    = (__hip_bfloat16*)(ws + 134217728);           //  41,943,040 (packed)
    float*          Yeq   = (float*)(ws + 176160768);                    //  67,108,864

    float* out_inv = out;                                  // [8192][512]
    float* out_eq  = out + (size_t)BROWS * NINV;           // [8192][3][128]

    hipLaunchKernelGGL(feats_kernel, dim3(BROWS), dim3(256), 0, stream,
                       t1, t2, u1, u2, feats);
    hipLaunchKernelGGL(wt_kernel, dim3(NTOT / 32, KF / 32), dim3(256), 0, stream,
                       W_inv, W_eq, WT);
    hipLaunchKernelGGL(gemm_kernel, dim3((NTOT / BN) * (BROWS / BM)), dim3(512), 0, stream,
                       feats, WT, b_inv, g_inv, be_inv, b_eq, g_eq, be_eq,
                       out_inv, Yeq);
    hipLaunchKernelGGL(eqcomb_kernel, dim3(BROWS), dim3(128), 0, stream,
                       Yeq, V1, V2, out_eq);
}

// Round 4
// 582.633 us; speedup vs baseline: 1.0487x; 1.0487x over previous
//
#include <hip/hip_runtime.h>
#include <hip/hip_bf16.h>

// Problem constants
#define BROWS 8192      // B*N = 8*1024
#define DDIM 3
#define CDIM 64
#define KF 8192         // F = 2*C*C
#define NINV 512
#define NEQ 1024        // per head
#define NTOT 2560       // 512 + 1024 + 1024
#define BAS 16
#define UEQ 64

// Packed-tile layouts (producers and GEMM agree):
//  A: tile (mb, kt) = 256 rows x 32 k bf16 = 16 KB at byte ((mb*256+kt) << 14)
//  B: tile (nb, kt) = 320 rows x 32 k bf16 = 20 KB at byte ((nb*256+kt) * 20480)
//  Within a tile, element (rloc, kk):
//    logical chunk lc = (kk>>3)&3, phys = (lc + (rloc>>1)) & 3  (bank swizzle)
//    byte = rloc*64 + phys*16 + (kk&7)*2
// Staging is a linear memcpy per tile.

typedef float f32x4 __attribute__((ext_vector_type(4)));
typedef __bf16 bf16x8_t __attribute__((ext_vector_type(8)));
typedef __bf16 bf16x4_t __attribute__((ext_vector_type(4)));

__device__ __forceinline__ void async_copy16(const void* g, void* l) {
    __builtin_amdgcn_global_load_lds(
        (__attribute__((address_space(1))) void*)(g),
        (__attribute__((address_space(3))) void*)(l), 16, 0, 0);
}

// ---------------------------------------------------------------------------
// Kernel 1: per-row l2norm + Gram blocks -> packed feats tiles [32][256][16KB]
// ---------------------------------------------------------------------------
__global__ __launch_bounds__(256) void feats_kernel(
    const float* __restrict__ t1, const float* __restrict__ t2,
    const float* __restrict__ u1, const float* __restrict__ u2,
    __hip_bfloat16* __restrict__ feats)
{
    const int row = blockIdx.x;
    const int tid = threadIdx.x;
    __shared__ float sT[2 * DDIM * CDIM];   // [head][d][c]
    __shared__ float sU[2 * DDIM * CDIM];   // scaled u

    const size_t base = (size_t)row * (DDIM * CDIM);
    if (tid < 192) {
        sT[tid]       = t1[base + tid];
        sT[192 + tid] = t2[base + tid];
        sU[tid]       = u1[base + tid];
        sU[192 + tid] = u2[base + tid];
    }
    __syncthreads();
    if (tid < 128) {
        const int h = tid >> 6, c = tid & 63;
        float* U = sU + h * 192;
        float sq = U[c] * U[c] + U[64 + c] * U[64 + c] + U[128 + c] * U[128 + c];
        float s = 1.0f / sqrtf(fmaxf(sq, 0.01f));
        U[c] *= s; U[64 + c] *= s; U[128 + c] *= s;
    }
    __syncthreads();
    // thread -> (h, i, j-half); covers one 32-k tile span = one packed 64B line
    const int h  = tid >> 7;            // 0..1
    const int i  = (tid >> 1) & 63;     // 0..63
    const int jh = (tid & 1) * 32;      // 0 or 32
    const float* T = sT + h * 192;
    const float* U = sU + h * 192;
    const float ti0 = T[i], ti1 = T[64 + i], ti2 = T[128 + i];

    const int kbase = h * 4096 + i * 64 + jh;   // 32-aligned global k
    const int kt    = kbase >> 5;
    const int mb    = row >> 8, rloc = row & 255;
    char* line = (char*)feats + (((size_t)(mb * 256 + kt)) << 14) + rloc * 64;

    #pragma unroll
    for (int g = 0; g < 4; ++g) {                 // logical chunk
        const int phys = (g + (rloc >> 1)) & 3;
        #pragma unroll
        for (int half = 0; half < 2; ++half) {
            const int j = jh + g * 8 + half * 4;  // within-head col, mult of 4
            const float4 u0 = *reinterpret_cast<const float4*>(U + j);
            const float4 u1 = *reinterpret_cast<const float4*>(U + 64 + j);
            const float4 u2 = *reinterpret_cast<const float4*>(U + 128 + j);
            bf16x4_t v;
            v[0] = (__bf16)(ti0 * u0.x + ti1 * u1.x + ti2 * u2.x);
            v[1] = (__bf16)(ti0 * u0.y + ti1 * u1.y + ti2 * u2.y);
            v[2] = (__bf16)(ti0 * u0.z + ti1 * u1.z + ti2 * u2.z);
            v[3] = (__bf16)(ti0 * u0.w + ti1 * u1.w + ti2 * u2.w);
            *reinterpret_cast<bf16x4_t*>(line + phys * 16 + half * 8) = v;
        }
    }
}

// ---------------------------------------------------------------------------
// Kernel 2: transpose+convert W (K x N fp32) -> packed WT tiles [8][256][20KB]
// ---------------------------------------------------------------------------
__global__ __launch_bounds__(256) void wt_kernel(
    const float* __restrict__ W_inv, const float* __restrict__ W_eq,
    __hip_bfloat16* __restrict__ WT)
{
    __shared__ float tile[32][33];
    const int tid = threadIdx.x;
    const int tx = tid & 31;          // n within tile (load)
    const int ty = tid >> 5;          // 0..7
    const int n0 = blockIdx.x * 32;   // output column block (0..2559)
    const int k0 = blockIdx.y * 32;   // K block (0..8191)

    const float* src; int ldn, nl0;
    if (n0 < NINV)            { src = W_inv;                       ldn = NINV; nl0 = n0; }
    else if (n0 < NINV + NEQ) { src = W_eq;                        ldn = NEQ;  nl0 = n0 - NINV; }
    else                      { src = W_eq + (size_t)KF * NEQ;     ldn = NEQ;  nl0 = n0 - NINV - NEQ; }

    #pragma unroll
    for (int i = 0; i < 4; ++i) {
        int kl = ty + i * 8;
        tile[kl][tx] = src[(size_t)(k0 + kl) * ldn + nl0 + tx];
    }
    __syncthreads();
    // store phase: each thread packs 4 consecutive k for one n (8 B store)
    const int n_l = tid >> 3;         // 0..31
    const int k4  = (tid & 7) * 4;    // 0..28
    bf16x4_t v;
    #pragma unroll
    for (int q = 0; q < 4; ++q) v[q] = (__bf16)tile[k4 + q][n_l];

    const int n    = n0 + n_l;
    const int nb   = n / 320, rloc = n - nb * 320;
    const int kt   = k0 >> 5;
    const int lc   = (k4 >> 3) & 3, e = k4 & 7;
    const int phys = (lc + (rloc >> 1)) & 3;
    char* dst = (char*)WT + ((size_t)(nb * 256 + kt)) * 20480
              + rloc * 64 + phys * 16 + e * 2;
    *reinterpret_cast<bf16x4_t*>(dst) = v;
}

// ---------------------------------------------------------------------------
// Kernel 3: bf16 MFMA GEMM on packed tiles. BM=256 x BN=320, grid = exactly
// 256 blocks (1/CU, no tail). 512 threads = 8 waves (4m x 2n), wave tile
// 64x160. 4 LDS buffers (144 KB), static indices.
// Waves 0-3 stage A (4 x 16B/phase), waves 4-7 stage B (5/phase).
// R3: merged 2-tile barrier windows — 1 barrier pair per 2 K-tiles (was 2
//     pairs), ISSUE moved after BAR2 (post-read of the overwritten bufs),
//     "memory" clobber between the two COMPUTEs lets tile-t MFMAs sink under
//     tile-(t+1) ds_reads (LDS/MFMA overlap). setprio reverted (R2: -6%).
// ---------------------------------------------------------------------------
#define BM 256
#define BN 320
#define BK 32
#define ATILE 16384
#define BTILE 20480

__global__ __launch_bounds__(512, 2) void gemm_kernel(
    const __hip_bfloat16* __restrict__ A,   // packed [32][256][16KB]
    const __hip_bfloat16* __restrict__ BT,  // packed [8][256][20KB]
    const float* __restrict__ b_inv, const float* __restrict__ g_inv,
    const float* __restrict__ be_inv,
    const float* __restrict__ b_eq,  const float* __restrict__ g_eq,
    const float* __restrict__ be_eq,
    float* __restrict__ out_inv,            // d_out: [BROWS][NINV]
    float* __restrict__ Yeq)                // ws:    [BROWS][2048]
{
    __shared__ alignas(16) __hip_bfloat16 AsBuf[4][BM * BK];  // 4 x 16 KB
    __shared__ alignas(16) __hip_bfloat16 BsBuf[4][BN * BK];  // 4 x 20 KB

    const int tid  = threadIdx.x;
    const int wave = tid >> 6;
    const int lane = tid & 63;
    const bool aWave = wave < 4;

    // 256 blocks: xcd = b%8 owns 4 contiguous m-stripes, n fastest.
    const int b    = blockIdx.x;
    const int xcd  = b & 7;
    const int slot = b >> 3;            // 0..31
    const int nb   = slot & 7;          // 0..7
    const int mb   = xcd * 4 + (slot >> 3);
    const int n0   = nb * BN;
    const int m0   = mb * BM;

    const char* pA = (const char*)A  + ((size_t)mb << 22);        // mb*4MB
    const char* pB = (const char*)BT + (size_t)nb * 256 * BTILE;  // nb*5MB

    // staging offsets (linear memcpy within a tile)
    const int aoff = wave * 4096 + lane * 16;         // waves 0-3
    const int boff = (wave - 4) * 5120 + lane * 16;   // waves 4-7

    // ds_read chunk swizzle (row-parity based, tile-term-independent)
    const int chnk = (((lane >> 4) + ((lane & 15) >> 1)) & 3) * 8;
    const int wm = (wave & 3) * 64;
    const int wn = (wave >> 2) * 160;
    const int l15 = lane & 15;

    f32x4 acc[4][10] = {};

#define ISSUE(bufi, t)                                                        \
    do {                                                                      \
        if (aWave) {                                                          \
            _Pragma("unroll")                                                 \
            for (int j = 0; j < 4; ++j)                                       \
                async_copy16(pA + (size_t)(t) * ATILE + aoff + j * 1024,      \
                             (char*)&AsBuf[bufi][0] + aoff + j * 1024);       \
        } else {                                                              \
            _Pragma("unroll")                                                 \
            for (int j = 0; j < 5; ++j)                                       \
                async_copy16(pB + (size_t)(t) * BTILE + boff + j * 1024,      \
                             (char*)&BsBuf[bufi][0] + boff + j * 1024);       \
        }                                                                     \
    } while (0)

#define COMPUTE(bufi)                                                         \
    do {                                                                      \
        bf16x8_t a_[4];                                                       \
        _Pragma("unroll")                                                     \
        for (int mt = 0; mt < 4; ++mt)                                        \
            a_[mt] = *reinterpret_cast<const bf16x8_t*>(                      \
                &AsBuf[bufi][(wm + mt * 16 + l15) * BK + chnk]);              \
        _Pragma("unroll")                                                     \
        for (int nt = 0; nt < 10; ++nt) {                                     \
            bf16x8_t b_ = *reinterpret_cast<const bf16x8_t*>(                 \
                &BsBuf[bufi][(wn + nt * 16 + l15) * BK + chnk]);              \
            _Pragma("unroll")                                                 \
            for (int mt = 0; mt < 4; ++mt)                                    \
                acc[mt][nt] = __builtin_amdgcn_mfma_f32_16x16x32_bf16(        \
                    a_[mt], b_, acc[mt][nt], 0, 0, 0);                        \
        }                                                                     \
    } while (0)

#define WAITAB(na, nb_)                                                       \
    do {                                                                      \
        if (aWave) asm volatile("s_waitcnt vmcnt(" #na ")" ::: "memory");     \
        else       asm volatile("s_waitcnt vmcnt(" #nb_ ")" ::: "memory");    \
    } while (0)

    // Merged phase: compute tiles (t, t+1) from bufs (b0, b1); then issue
    // tiles (t+4, t+5) into the bufs just freed. 1 barrier pair / 2 K-tiles.
#define MPHASE(b0, b1, t)                                                     \
    do {                                                                      \
        WAITAB(8, 10);                                                        \
        __builtin_amdgcn_s_barrier();                                         \
        asm volatile("" ::: "memory");                                        \
        COMPUTE(b0);                                                          \
        asm volatile("" ::: "memory");                                        \
        COMPUTE(b1);                                                          \
        asm volatile("" ::: "memory");                                        \
        __builtin_amdgcn_s_barrier();                                         \
        ISSUE(b0, t + 4);                                                     \
        ISSUE(b1, t + 5);                                                     \
    } while (0)

    // prologue: tiles 0..3 -> bufs 0..3
    ISSUE(0, 0);
    ISSUE(1, 1);
    ISSUE(2, 2);
    ISSUE(3, 3);

    for (int i = 0; i < 63; ++i) {
        const int t = i * 4;
        MPHASE(0, 1, t);          // computes t,t+1;   issues t+4,t+5
        MPHASE(2, 3, t + 2);      // computes t+2,t+3; issues t+6,t+7
    }
    // tail: tiles 252..255 in bufs 0..3 (no further issues)
    WAITAB(8, 10);
    __builtin_amdgcn_s_barrier();
    asm volatile("" ::: "memory");
    COMPUTE(0);
    asm volatile("" ::: "memory");
    COMPUTE(1);
    asm volatile("" ::: "memory");
    __builtin_amdgcn_s_barrier();

    asm volatile("s_waitcnt vmcnt(0)" ::: "memory");
    __builtin_amdgcn_s_barrier();
    asm volatile("" ::: "memory");
    COMPUTE(2);
    asm volatile("" ::: "memory");
    COMPUTE(3);

    // epilogue: y = relu(g * (acc + b) / sqrt(1.001) + be), params fused
    const float RSQ = 0.9995003746877732f;
    #pragma unroll
    for (int nt = 0; nt < 10; ++nt) {
        const int gn = n0 + wn + nt * 16 + l15;
        float bbp, gg, bep;
        if (gn < NINV) {
            bbp = b_inv[gn]; gg = g_inv[gn]; bep = be_inv[gn];
        } else {
            const int e = gn - NINV, hh = e >> 10, nl = e & 1023;
            bbp = b_eq[hh * NEQ + nl]; gg = g_eq[hh * NEQ + nl]; bep = be_eq[hh * NEQ + nl];
        }
        gg *= RSQ;
        #pragma unroll
        for (int mt = 0; mt < 4; ++mt) {
            const int gmb = m0 + wm + mt * 16 + ((lane >> 4) << 2);
            #pragma unroll
            for (int rr = 0; rr < 4; ++rr) {
                float y = fmaxf(gg * (acc[mt][nt][rr] + bbp) + bep, 0.0f);
                const size_t gm = gmb + rr;
                if (gn < NINV) out_inv[gm * NINV + gn] = y;
                else           Yeq[gm * 2048 + (gn - NINV)] = y;
            }
        }
    }
#undef MPHASE
#undef WAITAB
#undef COMPUTE
#undef ISSUE
}

// ---------------------------------------------------------------------------
// Kernel 4: basis recombine
// ---------------------------------------------------------------------------
__global__ __launch_bounds__(128) void eqcomb_kernel(
    const float* __restrict__ Yeq,   // [BROWS][2048]
    const float* __restrict__ V1, const float* __restrict__ V2,
    float* __restrict__ out_eq)      // [BROWS][3][128]
{
    const int row = blockIdx.x;
    const int tid = threadIdx.x;     // 128
    __shared__ float sV[2][DDIM][BAS];
    if (tid < 96) {
        const int h = tid / 48, rem = tid % 48;
        const float* V = h ? V2 : V1;
        sV[h][rem / BAS][rem % BAS] = V[(size_t)row * (DDIM * BAS) + rem];
    }
    __syncthreads();
    const int l = tid >> 6, u = tid & 63;
    const float4* y4 = reinterpret_cast<const float4*>(
        Yeq + (size_t)row * 2048 + l * 1024 + u * BAS);
    float a0 = 0.f, a1 = 0.f, a2 = 0.f;
    #pragma unroll
    for (int q = 0; q < 4; ++q) {
        float4 w = y4[q];
        const float* v0 = sV[l][0] + q * 4;
        const float* v1 = sV[l][1] + q * 4;
        const float* v2 = sV[l][2] + q * 4;
        a0 += w.x * v0[0] + w.y * v0[1] + w.z * v0[2] + w.w * v0[3];
        a1 += w.x * v1[0] + w.y * v1[1] + w.z * v1[2] + w.w * v1[3];
        a2 += w.x * v2[0] + w.y * v2[1] + w.z * v2[2] + w.w * v2[3];
    }
    float* o = out_eq + (size_t)row * (DDIM * 128);
    o[0 * 128 + l * 64 + u] = a0;
    o[1 * 128 + l * 64 + u] = a1;
    o[2 * 128 + l * 64 + u] = a2;
}

// ---------------------------------------------------------------------------
extern "C" void kernel_launch(void* const* d_in, const int* in_sizes, int n_in,
                              void* d_out, int out_size, void* d_ws, size_t ws_size,
                              hipStream_t stream) {
    const float* t1    = (const float*)d_in[0];
    const float* t2    = (const float*)d_in[1];
    const float* u1    = (const float*)d_in[2];
    const float* u2    = (const float*)d_in[3];
    const float* V1    = (const float*)d_in[4];
    const float* V2    = (const float*)d_in[5];
    const float* W_inv = (const float*)d_in[6];
    const float* b_inv = (const float*)d_in[7];
    const float* g_inv = (const float*)d_in[8];
    const float* be_inv= (const float*)d_in[9];
    const float* W_eq  = (const float*)d_in[10];
    const float* b_eq  = (const float*)d_in[11];
    const float* g_eq  = (const float*)d_in[12];
    const float* be_eq = (const float*)d_in[13];
    float* out = (float*)d_out;

    // workspace layout (bytes)
    char* ws = (char*)d_ws;
    __hip_bfloat16* feats = (__hip_bfloat16*)(ws);                       // 134,217,728 (packed)
    __hip_bfloat16* WT    = (__hip_bfloat16*)(ws + 134217728);           //  41,943,040 (packed)
    float*          Yeq   = (float*)(ws + 176160768);                    //  67,108,864

    float* out_inv = out;                                  // [8192][512]
    float* out_eq  = out + (size_t)BROWS * NINV;           // [8192][3][128]

    hipLaunchKernelGGL(feats_kernel, dim3(BROWS), dim3(256), 0, stream,
                       t1, t2, u1, u2, feats);
    hipLaunchKernelGGL(wt_kernel, dim3(NTOT / 32, KF / 32), dim3(256), 0, stream,
                       W_inv, W_eq, WT);
    hipLaunchKernelGGL(gemm_kernel, dim3((NTOT / BN) * (BROWS / BM)), dim3(512), 0, stream,
                       feats, WT, b_inv, g_inv, be_inv, b_eq, g_eq, be_eq,
                       out_inv, Yeq);
    hipLaunchKernelGGL(eqcomb_kernel, dim3(BROWS), dim3(128), 0, stream,
                       Yeq, V1, V2, out_eq);
}

// Round 5
// 546.416 us; speedup vs baseline: 1.1182x; 1.0663x over previous
//
#include <hip/hip_runtime.h>
#include <hip/hip_bf16.h>

// Problem constants
#define BROWS 8192      // B*N = 8*1024
#define DDIM 3
#define CDIM 64
#define KF 8192         // F = 2*C*C
#define NINV 512
#define NEQ 1024        // per head
#define NTOT 2560       // 512 + 1024 + 1024
#define BAS 16
#define UEQ 64

// Packed-tile layouts (producers and GEMM agree):
//  A: tile (mb, kt) = 256 rows x 32 k bf16 = 16 KB at byte ((mb*256+kt) << 14)
//  B: tile (nb, kt) = 320 rows x 32 k bf16 = 20 KB at byte ((nb*256+kt) * 20480)
//  Within a tile, element (rloc, kk):
//    logical chunk lc = (kk>>3)&3, phys = (lc + (rloc>>1)) & 3  (bank swizzle)
//    byte = rloc*64 + phys*16 + (kk&7)*2
// Staging is a linear memcpy per tile.

typedef float f32x4 __attribute__((ext_vector_type(4)));
typedef __bf16 bf16x8_t __attribute__((ext_vector_type(8)));
typedef __bf16 bf16x4_t __attribute__((ext_vector_type(4)));

__device__ __forceinline__ void async_copy16(const void* g, void* l) {
    __builtin_amdgcn_global_load_lds(
        (__attribute__((address_space(1))) void*)(g),
        (__attribute__((address_space(3))) void*)(l), 16, 0, 0);
}

// ---------------------------------------------------------------------------
// Kernel 1: per-row l2norm + Gram blocks -> packed feats tiles [32][256][16KB]
// R4 rewrite: 16 rows per block (512 blocks). Old version had adjacent lanes
// writing 8B pieces to lines 16KB apart (64 line-transactions per wave store,
// 8x amplification). Now: wave w owns kt = w*64..w*64+63; lane l = (row l>>2,
// phys l&3) -> per-iteration store is one contiguous 1024B burst.
// T/U staged in LDS, row stride 196 floats (196%32=4 -> 2-way bank = free).
// ---------------------------------------------------------------------------
#define FROWS 16
#define FSTRIDE 196

__global__ __launch_bounds__(256) void feats_kernel(
    const float* __restrict__ t1, const float* __restrict__ t2,
    const float* __restrict__ u1, const float* __restrict__ u2,
    __hip_bfloat16* __restrict__ feats)
{
    __shared__ float sT1[FROWS * FSTRIDE];
    __shared__ float sT2[FROWS * FSTRIDE];
    __shared__ float sU1[FROWS * FSTRIDE];
    __shared__ float sU2[FROWS * FSTRIDE];

    const int tid = threadIdx.x;
    const int r0  = blockIdx.x * FROWS;          // first row of this block

    // Phase 1: stage T,U (16 rows x 192 floats x 4 arrays), coalesced.
    #pragma unroll
    for (int k = 0; k < 12; ++k) {
        const int item = k * 256 + tid;          // < 3072
        const int r = item / 192, c = item - r * 192;
        const size_t g = (size_t)(r0 + r) * 192 + c;
        const int l = r * FSTRIDE + c;
        sT1[l] = t1[g];
        sT2[l] = t2[g];
        sU1[l] = u1[g];
        sU2[l] = u2[g];
    }
    __syncthreads();

    // Phase 2: l2-normalize U over d, per (row, head, c). 2048 items.
    #pragma unroll
    for (int k = 0; k < 8; ++k) {
        const int item = k * 256 + tid;          // < 2048
        const int r = item >> 7, rem = item & 127;
        const int h = rem >> 6, c = rem & 63;
        float* U = (h ? sU2 : sU1) + r * FSTRIDE;
        float sq = U[c] * U[c] + U[64 + c] * U[64 + c] + U[128 + c] * U[128 + c];
        float s = 1.0f / sqrtf(fmaxf(sq, 0.01f));
        U[c] *= s; U[64 + c] *= s; U[128 + c] *= s;
    }
    __syncthreads();

    // Phase 3: Gram compute + coalesced packed stores.
    const int w       = tid >> 6;        // wave 0..3 -> kt block
    const int lane    = tid & 63;
    const int r_local = lane >> 2;       // 0..15
    const int p       = lane & 3;        // phys chunk
    const int mb      = r0 >> 8;
    const int rloc0   = r0 & 255;
    const int rloc    = rloc0 + r_local;
    const int lc      = (p - (rloc >> 1)) & 3;   // invert phys swizzle
    const float* Tarr = (w >= 2 ? sT2 : sT1) + r_local * FSTRIDE;
    const float* Uarr = (w >= 2 ? sU2 : sU1) + r_local * FSTRIDE;

    char* dst = (char*)feats + (((size_t)(mb * 256 + w * 64)) << 14)
              + rloc0 * 64 + lane * 16;

    #pragma unroll 4
    for (int it = 0; it < 64; ++it) {
        const int kt = w * 64 + it;
        const int i  = (kt >> 1) & 63;
        const int jh = (kt & 1) * 32;
        const int j0 = jh + lc * 8;
        const float ti0 = Tarr[i], ti1 = Tarr[64 + i], ti2 = Tarr[128 + i];
        bf16x8_t vv;
        #pragma unroll
        for (int half = 0; half < 2; ++half) {
            const int j = j0 + half * 4;
            const float4 u0 = *reinterpret_cast<const float4*>(Uarr + j);
            const float4 u1_ = *reinterpret_cast<const float4*>(Uarr + 64 + j);
            const float4 u2_ = *reinterpret_cast<const float4*>(Uarr + 128 + j);
            vv[half * 4 + 0] = (__bf16)(ti0 * u0.x + ti1 * u1_.x + ti2 * u2_.x);
            vv[half * 4 + 1] = (__bf16)(ti0 * u0.y + ti1 * u1_.y + ti2 * u2_.y);
            vv[half * 4 + 2] = (__bf16)(ti0 * u0.z + ti1 * u1_.z + ti2 * u2_.z);
            vv[half * 4 + 3] = (__bf16)(ti0 * u0.w + ti1 * u1_.w + ti2 * u2_.w);
        }
        *reinterpret_cast<bf16x8_t*>(dst) = vv;   // 64 lanes x 16B = 1KB burst
        dst += 16384;
    }
}

// ---------------------------------------------------------------------------
// Kernel 2: transpose+convert W (K x N fp32) -> packed WT tiles [8][256][20KB]
// ---------------------------------------------------------------------------
__global__ __launch_bounds__(256) void wt_kernel(
    const float* __restrict__ W_inv, const float* __restrict__ W_eq,
    __hip_bfloat16* __restrict__ WT)
{
    __shared__ float tile[32][33];
    const int tid = threadIdx.x;
    const int tx = tid & 31;          // n within tile (load)
    const int ty = tid >> 5;          // 0..7
    const int n0 = blockIdx.x * 32;   // output column block (0..2559)
    const int k0 = blockIdx.y * 32;   // K block (0..8191)

    const float* src; int ldn, nl0;
    if (n0 < NINV)            { src = W_inv;                       ldn = NINV; nl0 = n0; }
    else if (n0 < NINV + NEQ) { src = W_eq;                        ldn = NEQ;  nl0 = n0 - NINV; }
    else                      { src = W_eq + (size_t)KF * NEQ;     ldn = NEQ;  nl0 = n0 - NINV - NEQ; }

    #pragma unroll
    for (int i = 0; i < 4; ++i) {
        int kl = ty + i * 8;
        tile[kl][tx] = src[(size_t)(k0 + kl) * ldn + nl0 + tx];
    }
    __syncthreads();
    // store phase: each thread packs 4 consecutive k for one n (8 B store)
    const int n_l = tid >> 3;         // 0..31
    const int k4  = (tid & 7) * 4;    // 0..28
    bf16x4_t v;
    #pragma unroll
    for (int q = 0; q < 4; ++q) v[q] = (__bf16)tile[k4 + q][n_l];

    const int n    = n0 + n_l;
    const int nb   = n / 320, rloc = n - nb * 320;
    const int kt   = k0 >> 5;
    const int lc   = (k4 >> 3) & 3, e = k4 & 7;
    const int phys = (lc + (rloc >> 1)) & 3;
    char* dst = (char*)WT + ((size_t)(nb * 256 + kt)) * 20480
              + rloc * 64 + phys * 16 + e * 2;
    *reinterpret_cast<bf16x4_t*>(dst) = v;
}

// ---------------------------------------------------------------------------
// Kernel 3: bf16 MFMA GEMM on packed tiles. BM=256 x BN=320, grid = exactly
// 256 blocks (1/CU, no tail). 512 threads = 8 waves (4m x 2n), wave tile
// 64x160. 4 LDS buffers (144 KB), static indices.
// Waves 0-3 stage A (4 x 16B/phase), waves 4-7 stage B (5/phase).
// R3: merged 2-tile barrier windows (neutral vs R1; kept). setprio: regressed
//     (R2, -6%) -> absent. MfmaUtil pinned ~37% across schedule variants.
// ---------------------------------------------------------------------------
#define BM 256
#define BN 320
#define BK 32
#define ATILE 16384
#define BTILE 20480

__global__ __launch_bounds__(512, 2) void gemm_kernel(
    const __hip_bfloat16* __restrict__ A,   // packed [32][256][16KB]
    const __hip_bfloat16* __restrict__ BT,  // packed [8][256][20KB]
    const float* __restrict__ b_inv, const float* __restrict__ g_inv,
    const float* __restrict__ be_inv,
    const float* __restrict__ b_eq,  const float* __restrict__ g_eq,
    const float* __restrict__ be_eq,
    float* __restrict__ out_inv,            // d_out: [BROWS][NINV]
    float* __restrict__ Yeq)                // ws:    [BROWS][2048]
{
    __shared__ alignas(16) __hip_bfloat16 AsBuf[4][BM * BK];  // 4 x 16 KB
    __shared__ alignas(16) __hip_bfloat16 BsBuf[4][BN * BK];  // 4 x 20 KB

    const int tid  = threadIdx.x;
    const int wave = tid >> 6;
    const int lane = tid & 63;
    const bool aWave = wave < 4;

    // 256 blocks: xcd = b%8 owns 4 contiguous m-stripes, n fastest.
    const int b    = blockIdx.x;
    const int xcd  = b & 7;
    const int slot = b >> 3;            // 0..31
    const int nb   = slot & 7;          // 0..7
    const int mb   = xcd * 4 + (slot >> 3);
    const int n0   = nb * BN;
    const int m0   = mb * BM;

    const char* pA = (const char*)A  + ((size_t)mb << 22);        // mb*4MB
    const char* pB = (const char*)BT + (size_t)nb * 256 * BTILE;  // nb*5MB

    // staging offsets (linear memcpy within a tile)
    const int aoff = wave * 4096 + lane * 16;         // waves 0-3
    const int boff = (wave - 4) * 5120 + lane * 16;   // waves 4-7

    // ds_read chunk swizzle (row-parity based, tile-term-independent)
    const int chnk = (((lane >> 4) + ((lane & 15) >> 1)) & 3) * 8;
    const int wm = (wave & 3) * 64;
    const int wn = (wave >> 2) * 160;
    const int l15 = lane & 15;

    f32x4 acc[4][10] = {};

#define ISSUE(bufi, t)                                                        \
    do {                                                                      \
        if (aWave) {                                                          \
            _Pragma("unroll")                                                 \
            for (int j = 0; j < 4; ++j)                                       \
                async_copy16(pA + (size_t)(t) * ATILE + aoff + j * 1024,      \
                             (char*)&AsBuf[bufi][0] + aoff + j * 1024);       \
        } else {                                                              \
            _Pragma("unroll")                                                 \
            for (int j = 0; j < 5; ++j)                                       \
                async_copy16(pB + (size_t)(t) * BTILE + boff + j * 1024,      \
                             (char*)&BsBuf[bufi][0] + boff + j * 1024);       \
        }                                                                     \
    } while (0)

#define COMPUTE(bufi)                                                         \
    do {                                                                      \
        bf16x8_t a_[4];                                                       \
        _Pragma("unroll")                                                     \
        for (int mt = 0; mt < 4; ++mt)                                        \
            a_[mt] = *reinterpret_cast<const bf16x8_t*>(                      \
                &AsBuf[bufi][(wm + mt * 16 + l15) * BK + chnk]);              \
        _Pragma("unroll")                                                     \
        for (int nt = 0; nt < 10; ++nt) {                                     \
            bf16x8_t b_ = *reinterpret_cast<const bf16x8_t*>(                 \
                &BsBuf[bufi][(wn + nt * 16 + l15) * BK + chnk]);              \
            _Pragma("unroll")                                                 \
            for (int mt = 0; mt < 4; ++mt)                                    \
                acc[mt][nt] = __builtin_amdgcn_mfma_f32_16x16x32_bf16(        \
                    a_[mt], b_, acc[mt][nt], 0, 0, 0);                        \
        }                                                                     \
    } while (0)

#define WAITAB(na, nb_)                                                       \
    do {                                                                      \
        if (aWave) asm volatile("s_waitcnt vmcnt(" #na ")" ::: "memory");     \
        else       asm volatile("s_waitcnt vmcnt(" #nb_ ")" ::: "memory");    \
    } while (0)

    // Merged phase: compute tiles (t, t+1) from bufs (b0, b1); then issue
    // tiles (t+4, t+5) into the bufs just freed. 1 barrier pair / 2 K-tiles.
#define MPHASE(b0, b1, t)                                                     \
    do {                                                                      \
        WAITAB(8, 10);                                                        \
        __builtin_amdgcn_s_barrier();                                         \
        asm volatile("" ::: "memory");                                        \
        COMPUTE(b0);                                                          \
        asm volatile("" ::: "memory");                                        \
        COMPUTE(b1);                                                          \
        asm volatile("" ::: "memory");                                        \
        __builtin_amdgcn_s_barrier();                                         \
        ISSUE(b0, t + 4);                                                     \
        ISSUE(b1, t + 5);                                                     \
    } while (0)

    // prologue: tiles 0..3 -> bufs 0..3
    ISSUE(0, 0);
    ISSUE(1, 1);
    ISSUE(2, 2);
    ISSUE(3, 3);

    for (int i = 0; i < 63; ++i) {
        const int t = i * 4;
        MPHASE(0, 1, t);          // computes t,t+1;   issues t+4,t+5
        MPHASE(2, 3, t + 2);      // computes t+2,t+3; issues t+6,t+7
    }
    // tail: tiles 252..255 in bufs 0..3 (no further issues)
    WAITAB(8, 10);
    __builtin_amdgcn_s_barrier();
    asm volatile("" ::: "memory");
    COMPUTE(0);
    asm volatile("" ::: "memory");
    COMPUTE(1);
    asm volatile("" ::: "memory");
    __builtin_amdgcn_s_barrier();

    asm volatile("s_waitcnt vmcnt(0)" ::: "memory");
    __builtin_amdgcn_s_barrier();
    asm volatile("" ::: "memory");
    COMPUTE(2);
    asm volatile("" ::: "memory");
    COMPUTE(3);

    // epilogue: y = relu(g * (acc + b) / sqrt(1.001) + be), params fused
    const float RSQ = 0.9995003746877732f;
    #pragma unroll
    for (int nt = 0; nt < 10; ++nt) {
        const int gn = n0 + wn + nt * 16 + l15;
        float bbp, gg, bep;
        if (gn < NINV) {
            bbp = b_inv[gn]; gg = g_inv[gn]; bep = be_inv[gn];
        } else {
            const int e = gn - NINV, hh = e >> 10, nl = e & 1023;
            bbp = b_eq[hh * NEQ + nl]; gg = g_eq[hh * NEQ + nl]; bep = be_eq[hh * NEQ + nl];
        }
        gg *= RSQ;
        #pragma unroll
        for (int mt = 0; mt < 4; ++mt) {
            const int gmb = m0 + wm + mt * 16 + ((lane >> 4) << 2);
            #pragma unroll
            for (int rr = 0; rr < 4; ++rr) {
                float y = fmaxf(gg * (acc[mt][nt][rr] + bbp) + bep, 0.0f);
                const size_t gm = gmb + rr;
                if (gn < NINV) out_inv[gm * NINV + gn] = y;
                else           Yeq[gm * 2048 + (gn - NINV)] = y;
            }
        }
    }
#undef MPHASE
#undef WAITAB
#undef COMPUTE
#undef ISSUE
}

// ---------------------------------------------------------------------------
// Kernel 4: basis recombine
// ---------------------------------------------------------------------------
__global__ __launch_bounds__(128) void eqcomb_kernel(
    const float* __restrict__ Yeq,   // [BROWS][2048]
    const float* __restrict__ V1, const float* __restrict__ V2,
    float* __restrict__ out_eq)      // [BROWS][3][128]
{
    const int row = blockIdx.x;
    const int tid = threadIdx.x;     // 128
    __shared__ float sV[2][DDIM][BAS];
    if (tid < 96) {
        const int h = tid / 48, rem = tid % 48;
        const float* V = h ? V2 : V1;
        sV[h][rem / BAS][rem % BAS] = V[(size_t)row * (DDIM * BAS) + rem];
    }
    __syncthreads();
    const int l = tid >> 6, u = tid & 63;
    const float4* y4 = reinterpret_cast<const float4*>(
        Yeq + (size_t)row * 2048 + l * 1024 + u * BAS);
    float a0 = 0.f, a1 = 0.f, a2 = 0.f;
    #pragma unroll
    for (int q = 0; q < 4; ++q) {
        float4 w = y4[q];
        const float* v0 = sV[l][0] + q * 4;
        const float* v1 = sV[l][1] + q * 4;
        const float* v2 = sV[l][2] + q * 4;
        a0 += w.x * v0[0] + w.y * v0[1] + w.z * v0[2] + w.w * v0[3];
        a1 += w.x * v1[0] + w.y * v1[1] + w.z * v1[2] + w.w * v1[3];
        a2 += w.x * v2[0] + w.y * v2[1] + w.z * v2[2] + w.w * v2[3];
    }
    float* o = out_eq + (size_t)row * (DDIM * 128);
    o[0 * 128 + l * 64 + u] = a0;
    o[1 * 128 + l * 64 + u] = a1;
    o[2 * 128 + l * 64 + u] = a2;
}

// ---------------------------------------------------------------------------
extern "C" void kernel_launch(void* const* d_in, const int* in_sizes, int n_in,
                              void* d_out, int out_size, void* d_ws, size_t ws_size,
                              hipStream_t stream) {
    const float* t1    = (const float*)d_in[0];
    const float* t2    = (const float*)d_in[1];
    const float* u1    = (const float*)d_in[2];
    const float* u2    = (const float*)d_in[3];
    const float* V1    = (const float*)d_in[4];
    const float* V2    = (const float*)d_in[5];
    const float* W_inv = (const float*)d_in[6];
    const float* b_inv = (const float*)d_in[7];
    const float* g_inv = (const float*)d_in[8];
    const float* be_inv= (const float*)d_in[9];
    const float* W_eq  = (const float*)d_in[10];
    const float* b_eq  = (const float*)d_in[11];
    const float* g_eq  = (const float*)d_in[12];
    const float* be_eq = (const float*)d_in[13];
    float* out = (float*)d_out;

    // workspace layout (bytes)
    char* ws = (char*)d_ws;
    __hip_bfloat16* feats = (__hip_bfloat16*)(ws);                       // 134,217,728 (packed)
    __hip_bfloat16* WT    = (__hip_bfloat16*)(ws + 134217728);           //  41,943,040 (packed)
    float*          Yeq   = (float*)(ws + 176160768);                    //  67,108,864

    float* out_inv = out;                                  // [8192][512]
    float* out_eq  = out + (size_t)BROWS * NINV;           // [8192][3][128]

    hipLaunchKernelGGL(feats_kernel, dim3(BROWS / FROWS), dim3(256), 0, stream,
                       t1, t2, u1, u2, feats);
    hipLaunchKernelGGL(wt_kernel, dim3(NTOT / 32, KF / 32), dim3(256), 0, stream,
                       W_inv, W_eq, WT);
    hipLaunchKernelGGL(gemm_kernel, dim3((NTOT / BN) * (BROWS / BM)), dim3(512), 0, stream,
                       feats, WT, b_inv, g_inv, be_inv, b_eq, g_eq, be_eq,
                       out_inv, Yeq);
    hipLaunchKernelGGL(eqcomb_kernel, dim3(BROWS), dim3(128), 0, stream,
                       Yeq, V1, V2, out_eq);
}